// Round 8
// baseline (247.885 us; speedup 1.0000x reference)
//
#include <hip/hip_runtime.h>

typedef unsigned short u16;
typedef __bf16 bf16x8 __attribute__((ext_vector_type(8)));
typedef float f32x4 __attribute__((ext_vector_type(4)));

#define Bn 4
#define Sn 2048
#define Dn 1024
#define Hn 16
#define HDn 64

__device__ inline u16 f2bf(float f) {
  unsigned u = __builtin_bit_cast(unsigned, f);
  u += 0x7fffu + ((u >> 16) & 1u);
  return (u16)(u >> 16);
}

// async global->LDS DMA, 16B/lane; LDS dest = wave base + lane*16 [m97]
__device__ __forceinline__ void gl2lds16(const u16* g, u16* l) {
  __builtin_amdgcn_global_load_lds(
      (const __attribute__((address_space(1))) unsigned int*)g,
      (__attribute__((address_space(3))) unsigned int*)l, 16, 0, 0);
}

__device__ __forceinline__ float fexp2(float x) {
  return __builtin_amdgcn_exp2f(x);
}

// pack two f32 -> two bf16 (truncating) in one v_perm
__device__ __forceinline__ unsigned pk_bf_trunc(float lo, float hi) {
  return __builtin_amdgcn_perm(__builtin_bit_cast(unsigned, hi),
                               __builtin_bit_cast(unsigned, lo), 0x07060302u);
}

// ---- elementwise fp32 -> bf16 convert (x) ----
__global__ __launch_bounds__(256) void cvt4(const float* __restrict__ in,
                                            u16* __restrict__ out, int n4) {
  int i = blockIdx.x * 256 + threadIdx.x;
  if (i < n4) {
    float4 v = ((const float4*)in)[i];
    ushort4 o;
    o.x = f2bf(v.x); o.y = f2bf(v.y); o.z = f2bf(v.z); o.w = f2bf(v.w);
    ((ushort4*)out)[i] = o;
  }
}

// ---- transpose + convert 4 weights in one launch: out[z][n][k] = in_z[k][n] ----
__global__ __launch_bounds__(256) void tcvt4(const float* __restrict__ w0,
                                             const float* __restrict__ w1,
                                             const float* __restrict__ w2,
                                             const float* __restrict__ w3,
                                             u16* __restrict__ out) {
  __shared__ u16 tile[32][33];
  const float* in = (blockIdx.z == 0) ? w0 : (blockIdx.z == 1) ? w1
                   : (blockIdx.z == 2) ? w2 : w3;
  u16* dst = out + (size_t)blockIdx.z * Dn * Dn;
  int bx = blockIdx.x * 32;
  int by = blockIdx.y * 32;
  int tx = threadIdx.x & 31;
  int ty = threadIdx.x >> 5;
#pragma unroll
  for (int r = 0; r < 32; r += 8)
    tile[ty + r][tx] = f2bf(in[(size_t)(by + ty + r) * Dn + bx + tx]);
  __syncthreads();
#pragma unroll
  for (int r = 0; r < 32; r += 8)
    dst[(size_t)(bx + ty + r) * Dn + by + tx] = tile[tx][ty + r];
}

// ---- fused QKV gemm: [8192 x 3072], 256x128 tile, BK=64 ----
// wave tile 128x64 (2x2 wave grid). cols 0..1023: Q (scaled) -> qkb (stride
// 2048); 1024..2047: K -> qkb+1024; 2048..3071: V -> transposed scatter.
__global__ __launch_bounds__(256, 2) void gemm_qkv(const u16* __restrict__ A,
                                                   const u16* __restrict__ Bt,
                                                   u16* __restrict__ qkb,
                                                   u16* __restrict__ vt,
                                                   float qscale) {
  __shared__ __attribute__((aligned(16))) u16 As[2][256][32];  // 32 KB
  __shared__ __attribute__((aligned(16))) u16 Bs[2][128][32];  // 16 KB
  const int K = Dn;
  const int t = threadIdx.x;
  const int wave = t >> 6;
  const int lane = t & 63;
  const int lcol = lane & 15;
  const int quad = lane >> 4;
  const int wm = (wave >> 1) * 128;
  const int wn = (wave & 1) * 64;
  const int bm = blockIdx.y * 256;
  const int bn = blockIdx.x * 128;

  const int srow = lane >> 2;
  const int sseg = (lane & 3) * 8;
  const u16* a0p = A + (size_t)(bm + wave * 16 + srow) * K + sseg;
  const u16* a1p = a0p + (size_t)64 * K;
  const u16* a2p = a0p + (size_t)128 * K;
  const u16* a3p = a0p + (size_t)192 * K;
  const u16* b0p = Bt + (size_t)(bn + wave * 16 + srow) * K + sseg;
  const u16* b1p = b0p + (size_t)64 * K;
  u16* asl = &As[0][0][0] + wave * 512 + lane * 8;   // +2048/row-block, +8192/plane
  u16* bsl = &Bs[0][0][0] + wave * 512 + lane * 8;   // +2048/row-block, +4096/plane

  f32x4 acc[8][4];
#pragma unroll
  for (int i = 0; i < 8; i++)
#pragma unroll
    for (int j = 0; j < 4; j++) acc[i][j] = (f32x4){0.f, 0.f, 0.f, 0.f};

  for (int k0 = 0; k0 < K; k0 += 64) {
    gl2lds16(a0p + k0, asl);
    gl2lds16(a1p + k0, asl + 2048);
    gl2lds16(a2p + k0, asl + 4096);
    gl2lds16(a3p + k0, asl + 6144);
    gl2lds16(a0p + k0 + 32, asl + 8192);
    gl2lds16(a1p + k0 + 32, asl + 10240);
    gl2lds16(a2p + k0 + 32, asl + 12288);
    gl2lds16(a3p + k0 + 32, asl + 14336);
    gl2lds16(b0p + k0, bsl);
    gl2lds16(b1p + k0, bsl + 2048);
    gl2lds16(b0p + k0 + 32, bsl + 4096);
    gl2lds16(b1p + k0 + 32, bsl + 6144);
    __syncthreads();
#pragma unroll
    for (int ks = 0; ks < 2; ks++) {
      bf16x8 af[8], bf[4];
#pragma unroll
      for (int mi = 0; mi < 8; mi++)
        af[mi] = *(const bf16x8*)(&As[ks][wm + mi * 16 + lcol][quad * 8]);
#pragma unroll
      for (int ni = 0; ni < 4; ni++)
        bf[ni] = *(const bf16x8*)(&Bs[ks][wn + ni * 16 + lcol][quad * 8]);
#pragma unroll
      for (int mi = 0; mi < 8; mi++)
#pragma unroll
        for (int ni = 0; ni < 4; ni++)
          acc[mi][ni] = __builtin_amdgcn_mfma_f32_16x16x32_bf16(af[mi], bf[ni], acc[mi][ni], 0, 0, 0);
    }
    __syncthreads();
  }

  if (bn >= 2048) {
    const int b = bm >> 11;   // 256-row tiles never cross a batch (2048 rows)
#pragma unroll
    for (int mi = 0; mi < 8; mi++) {
#pragma unroll
      for (int ni = 0; ni < 4; ni++) {
        int row0 = bm + wm + mi * 16 + quad * 4;
        int s = row0 & (Sn - 1);
        int vcol = bn + wn + ni * 16 + lcol - 2048;
        int bh = (b << 4) + (vcol >> 6);
        int hd = vcol & 63;
        unsigned d0 = (unsigned)f2bf(acc[mi][ni][0]) |
                      ((unsigned)f2bf(acc[mi][ni][1]) << 16);
        unsigned d1 = (unsigned)f2bf(acc[mi][ni][2]) |
                      ((unsigned)f2bf(acc[mi][ni][3]) << 16);
        *(uint2*)(vt + ((size_t)bh * HDn + hd) * Sn + s) = (uint2){d0, d1};
      }
    }
  } else {
    const float scale = (bn < 1024) ? qscale : 1.0f;
#pragma unroll
    for (int mi = 0; mi < 8; mi++) {
#pragma unroll
      for (int ni = 0; ni < 4; ni++) {
#pragma unroll
        for (int r = 0; r < 4; r++) {
          int row = bm + wm + mi * 16 + quad * 4 + r;
          int col = bn + wn + ni * 16 + lcol;
          qkb[(size_t)row * 2048 + col] = f2bf(acc[mi][ni][r] * scale);
        }
      }
    }
  }
}

// ---- output gemm: [8192 x 1024] fp32+bias, 128x128 tile, BK=64 ----
__global__ __launch_bounds__(256) void gemm_out(const u16* __restrict__ A,
                                                const u16* __restrict__ Bt,
                                                float* __restrict__ Cout,
                                                const float* __restrict__ bias) {
  __shared__ __attribute__((aligned(16))) u16 As[2][128][32];
  __shared__ __attribute__((aligned(16))) u16 Bs[2][128][32];
  const int K = Dn;
  const int t = threadIdx.x;
  const int wave = t >> 6;
  const int lane = t & 63;
  const int lcol = lane & 15;
  const int quad = lane >> 4;
  const int wm = (wave >> 1) * 64;
  const int wn = (wave & 1) * 64;
  const int bm = blockIdx.y * 128;
  const int bn = blockIdx.x * 128;

  const int srow = lane >> 2;
  const int sseg = (lane & 3) * 8;
  const u16* a0p = A + (size_t)(bm + wave * 16 + srow) * K + sseg;
  const u16* a1p = a0p + (size_t)64 * K;
  const u16* b0p = Bt + (size_t)(bn + wave * 16 + srow) * K + sseg;
  const u16* b1p = b0p + (size_t)64 * K;
  u16* asl = &As[0][0][0] + wave * 512 + lane * 8;
  u16* bsl = &Bs[0][0][0] + wave * 512 + lane * 8;

  f32x4 acc[4][4];
#pragma unroll
  for (int i = 0; i < 4; i++)
#pragma unroll
    for (int j = 0; j < 4; j++) acc[i][j] = (f32x4){0.f, 0.f, 0.f, 0.f};

  for (int k0 = 0; k0 < K; k0 += 64) {
    gl2lds16(a0p + k0, asl);
    gl2lds16(a1p + k0, asl + 2048);
    gl2lds16(a0p + k0 + 32, asl + 4096);
    gl2lds16(a1p + k0 + 32, asl + 6144);
    gl2lds16(b0p + k0, bsl);
    gl2lds16(b1p + k0, bsl + 2048);
    gl2lds16(b0p + k0 + 32, bsl + 4096);
    gl2lds16(b1p + k0 + 32, bsl + 6144);
    __syncthreads();
#pragma unroll
    for (int ks = 0; ks < 2; ks++) {
      bf16x8 af[4], bf[4];
#pragma unroll
      for (int mi = 0; mi < 4; mi++)
        af[mi] = *(const bf16x8*)(&As[ks][wm + mi * 16 + lcol][quad * 8]);
#pragma unroll
      for (int ni = 0; ni < 4; ni++)
        bf[ni] = *(const bf16x8*)(&Bs[ks][wn + ni * 16 + lcol][quad * 8]);
#pragma unroll
      for (int mi = 0; mi < 4; mi++)
#pragma unroll
        for (int ni = 0; ni < 4; ni++)
          acc[mi][ni] = __builtin_amdgcn_mfma_f32_16x16x32_bf16(af[mi], bf[ni], acc[mi][ni], 0, 0, 0);
    }
    __syncthreads();
  }

#pragma unroll
  for (int mi = 0; mi < 4; mi++) {
#pragma unroll
    for (int ni = 0; ni < 4; ni++) {
#pragma unroll
      for (int r = 0; r < 4; r++) {
        int row = bm + wm + mi * 16 + quad * 4 + r;
        int col = bn + wn + ni * 16 + lcol;
        Cout[(size_t)row * Dn + col] = acc[mi][ni][r] + bias[col];
      }
    }
  }
}

// ---- causal flash attention v5: paired strips for uniform load ----
// Block = 4 waves. Pair p handles q-strips p (short) and 15-p (long), sharing
// K/V staging. S^T orientation, no-max softmax in exp2 domain.
__global__ __launch_bounds__(256, 2) void attn5(const u16* __restrict__ QK,
                                                const u16* __restrict__ Vt,
                                                u16* __restrict__ ctx) {
  __shared__ __attribute__((aligned(16))) u16 Ks2[2][64][32];
  __shared__ __attribute__((aligned(16))) u16 Vts2[2][64][32];
  __shared__ __attribute__((aligned(16))) u16 Pt[4][32][72];

  const int bh = blockIdx.x;
  const int b = bh >> 4, h = bh & 15;
  const int pair = blockIdx.y;           // 0..7
  const int t = threadIdx.x;
  const int w = t >> 6;
  const int lane = t & 63;
  const int lcol = lane & 15;
  const int quad = lane >> 4;
  const int qw0 = pair * 128 + w * 32;          // short strip wave base
  const int qw1 = (15 - pair) * 128 + w * 32;   // long strip wave base

  const size_t qkbase = ((size_t)b * Sn) * 2048 + h * HDn;
  const size_t obase = ((size_t)b * Sn) * Dn + h * HDn;
  const size_t vbase = ((size_t)bh * HDn) * Sn;

  bf16x8 qf[2][2][2];  // [strip][qb][kc]
#pragma unroll
  for (int si = 0; si < 2; si++) {
    const int qws = si ? qw1 : qw0;
#pragma unroll
    for (int qb = 0; qb < 2; qb++) {
      const u16* qp = QK + qkbase + (size_t)(qws + qb * 16 + lcol) * 2048 + quad * 8;
      qf[si][qb][0] = *(const bf16x8*)qp;
      qf[si][qb][1] = *(const bf16x8*)(qp + 32);
    }
  }

  f32x4 o[2][2][4];  // [strip][qb][nb]
#pragma unroll
  for (int si = 0; si < 2; si++)
#pragma unroll
    for (int qb = 0; qb < 2; qb++)
#pragma unroll
      for (int nb = 0; nb < 4; nb++) o[si][qb][nb] = (f32x4){0.f, 0.f, 0.f, 0.f};
  float lsum[2][2] = {{0.f, 0.f}, {0.f, 0.f}};

  const int srow = lane >> 2;
  const int sseg = (lane & 3) * 8;
  const u16* kp0 = QK + qkbase + 1024 + (size_t)(w * 16 + srow) * 2048 + sseg;
  const u16* vp0 = Vt + vbase + (size_t)(w * 16 + srow) * Sn + sseg;
  u16* ksl0 = &Ks2[0][0][0] + w * 512 + lane * 8;
  u16* ksl1 = ksl0 + 2048;
  u16* vsl0 = &Vts2[0][0][0] + w * 512 + lane * 8;
  u16* vsl1 = vsl0 + 2048;

  auto do_strip = [&](int si, int qw, int j0) {
    f32x4 s[4][2];
#pragma unroll
    for (int mb = 0; mb < 4; mb++) {
      bf16x8 kf0 = *(const bf16x8*)(&Ks2[0][mb * 16 + lcol][quad * 8]);
      bf16x8 kf1 = *(const bf16x8*)(&Ks2[1][mb * 16 + lcol][quad * 8]);
#pragma unroll
      for (int qb = 0; qb < 2; qb++) {
        f32x4 a = (f32x4){0.f, 0.f, 0.f, 0.f};
        a = __builtin_amdgcn_mfma_f32_16x16x32_bf16(kf0, qf[si][qb][0], a, 0, 0, 0);
        a = __builtin_amdgcn_mfma_f32_16x16x32_bf16(kf1, qf[si][qb][1], a, 0, 0, 0);
        s[mb][qb] = a;
      }
    }

    const bool needmask = (j0 + 63 > qw);
#pragma unroll
    for (int qb = 0; qb < 2; qb++) {
      const int qrow = qw + qb * 16 + lcol;
#pragma unroll
      for (int mb = 0; mb < 4; mb++) {
        float p[4];
#pragma unroll
        for (int r = 0; r < 4; r++) p[r] = fexp2(s[mb][qb][r]);
        if (needmask) {
          const int kvb = j0 + mb * 16 + quad * 4;
#pragma unroll
          for (int r = 0; r < 4; r++)
            if (kvb + r > qrow) p[r] = 0.f;
        }
        lsum[si][qb] += (p[0] + p[1]) + (p[2] + p[3]);
        unsigned d0 = pk_bf_trunc(p[0], p[1]);
        unsigned d1 = pk_bf_trunc(p[2], p[3]);
        *(uint2*)(&Pt[w][qb * 16 + lcol][mb * 16 + quad * 4]) = (uint2){d0, d1};
      }
    }

#pragma unroll
    for (int c = 0; c < 2; c++) {
      bf16x8 pf0 = *(const bf16x8*)(&Pt[w][lcol][c * 32 + quad * 8]);
      bf16x8 pf1 = *(const bf16x8*)(&Pt[w][16 + lcol][c * 32 + quad * 8]);
#pragma unroll
      for (int nb = 0; nb < 4; nb++) {
        bf16x8 vf = *(const bf16x8*)(&Vts2[c][nb * 16 + lcol][quad * 8]);
        o[si][0][nb] = __builtin_amdgcn_mfma_f32_16x16x32_bf16(vf, pf0, o[si][0][nb], 0, 0, 0);
        o[si][1][nb] = __builtin_amdgcn_mfma_f32_16x16x32_bf16(vf, pf1, o[si][1][nb], 0, 0, 0);
      }
    }
  };

  const int n_kv = (15 - pair) * 128 + 128;  // long strip upper bound

  for (int j0 = 0; j0 < n_kv; j0 += 64) {
    {
      const u16* kp = kp0 + (size_t)j0 * 2048;
      gl2lds16(kp, ksl0);
      gl2lds16(kp + 32, ksl1);
      const u16* vp = vp0 + j0;
      gl2lds16(vp, vsl0);
      gl2lds16(vp + 32, vsl1);
    }
    __syncthreads();

    if (j0 <= qw1 + 31) do_strip(1, qw1, j0);  // long strip
    if (j0 <= qw0 + 31) do_strip(0, qw0, j0);  // short strip
    __syncthreads();
  }

#pragma unroll
  for (int si = 0; si < 2; si++) {
    const int qws = si ? qw1 : qw0;
#pragma unroll
    for (int qb = 0; qb < 2; qb++) {
      float l = lsum[si][qb];
      l += __shfl_xor(l, 16);
      l += __shfl_xor(l, 32);
      float inv = 1.0f / l;
#pragma unroll
      for (int nb = 0; nb < 4; nb++) {
        unsigned d0 = (unsigned)f2bf(o[si][qb][nb][0] * inv) |
                      ((unsigned)f2bf(o[si][qb][nb][1] * inv) << 16);
        unsigned d1 = (unsigned)f2bf(o[si][qb][nb][2] * inv) |
                      ((unsigned)f2bf(o[si][qb][nb][3] * inv) << 16);
        u16* p = ctx + obase + (size_t)(qws + qb * 16 + lcol) * Dn + nb * 16 + quad * 4;
        *(uint2*)p = (uint2){d0, d1};
      }
    }
  }
}

extern "C" void kernel_launch(void* const* d_in, const int* in_sizes, int n_in,
                              void* d_out, int out_size, void* d_ws, size_t ws_size,
                              hipStream_t stream) {
  const float* x  = (const float*)d_in[0];
  const float* Wq = (const float*)d_in[1];
  const float* Wk = (const float*)d_in[2];
  const float* Wv = (const float*)d_in[3];
  const float* Wo = (const float*)d_in[4];
  const float* bo = (const float*)d_in[5];
  float* out = (float*)d_out;

  const size_t BSD = (size_t)Bn * Sn * Dn;
  const size_t DD = (size_t)Dn * Dn;

  u16* xb    = (u16*)d_ws;           // BSD
  u16* wall  = xb + BSD;             // 4*DD  (Wq^T, Wk^T, Wv^T, Wo^T)
  u16* qkb   = wall + 4 * DD;        // 2*BSD
  u16* vt    = qkb + 2 * BSD;        // BSD
  u16* cb    = vt + BSD;             // BSD

  cvt4<<<(int)(BSD / 4 / 256), 256, 0, stream>>>(x, xb, (int)(BSD / 4));
  tcvt4<<<dim3(Dn / 32, Dn / 32, 4), 256, 0, stream>>>(Wq, Wk, Wv, Wo, wall);

  // fused QKV projection: 256x128 tiles, 768 blocks
  gemm_qkv<<<dim3(3072 / 128, (Bn * Sn) / 256), 256, 0, stream>>>(
      xb, wall, qkb, vt, 0.125f * 1.44269504f);

  attn5<<<dim3(Bn * Hn, 8), 256, 0, stream>>>(qkb, vt, cb);

  // output projection: 128x128 tiles, 512 blocks
  gemm_out<<<dim3(Dn / 128, (Bn * Sn) / 128), 256, 0, stream>>>(cb, wall + 3 * DD, out, bo);
}

// Round 9
// 238.410 us; speedup vs baseline: 1.0397x; 1.0397x over previous
//
#include <hip/hip_runtime.h>

typedef unsigned short u16;
typedef __bf16 bf16x8 __attribute__((ext_vector_type(8)));
typedef float f32x4 __attribute__((ext_vector_type(4)));

#define Bn 4
#define Sn 2048
#define Dn 1024
#define Hn 16
#define HDn 64

__device__ inline u16 f2bf(float f) {
  unsigned u = __builtin_bit_cast(unsigned, f);
  u += 0x7fffu + ((u >> 16) & 1u);
  return (u16)(u >> 16);
}

// async global->LDS DMA, 16B/lane; LDS dest = wave base + lane*16 [m97]
__device__ __forceinline__ void gl2lds16(const u16* g, u16* l) {
  __builtin_amdgcn_global_load_lds(
      (const __attribute__((address_space(1))) unsigned int*)g,
      (__attribute__((address_space(3))) unsigned int*)l, 16, 0, 0);
}

__device__ __forceinline__ float fexp2(float x) {
  return __builtin_amdgcn_exp2f(x);
}

// pack two f32 -> two bf16 (truncating) in one v_perm
__device__ __forceinline__ unsigned pk_bf_trunc(float lo, float hi) {
  return __builtin_amdgcn_perm(__builtin_bit_cast(unsigned, hi),
                               __builtin_bit_cast(unsigned, lo), 0x07060302u);
}

// ---- elementwise fp32 -> bf16 convert (x) ----
__global__ __launch_bounds__(256) void cvt4(const float* __restrict__ in,
                                            u16* __restrict__ out, int n4) {
  int i = blockIdx.x * 256 + threadIdx.x;
  if (i < n4) {
    float4 v = ((const float4*)in)[i];
    ushort4 o;
    o.x = f2bf(v.x); o.y = f2bf(v.y); o.z = f2bf(v.z); o.w = f2bf(v.w);
    ((ushort4*)out)[i] = o;
  }
}

// ---- transpose + convert 4 weights in one launch: out[z][n][k] = in_z[k][n] ----
__global__ __launch_bounds__(256) void tcvt4(const float* __restrict__ w0,
                                             const float* __restrict__ w1,
                                             const float* __restrict__ w2,
                                             const float* __restrict__ w3,
                                             u16* __restrict__ out) {
  __shared__ u16 tile[32][33];
  const float* in = (blockIdx.z == 0) ? w0 : (blockIdx.z == 1) ? w1
                   : (blockIdx.z == 2) ? w2 : w3;
  u16* dst = out + (size_t)blockIdx.z * Dn * Dn;
  int bx = blockIdx.x * 32;
  int by = blockIdx.y * 32;
  int tx = threadIdx.x & 31;
  int ty = threadIdx.x >> 5;
#pragma unroll
  for (int r = 0; r < 32; r += 8)
    tile[ty + r][tx] = f2bf(in[(size_t)(by + ty + r) * Dn + bx + tx]);
  __syncthreads();
#pragma unroll
  for (int r = 0; r < 32; r += 8)
    dst[(size_t)(bx + ty + r) * Dn + by + tx] = tile[tx][ty + r];
}

// ---- fused QKV gemm: [8192 x 3072], 128x128 tile, BK=64, DBUF DMA ----
// Single barrier/iter: sync -> prefetch(next -> other buf) -> compute(cur).
// cols 0..1023: Q (scaled) -> qkb (stride 2048); 1024..2047: K -> qkb+1024;
// 2048..3071: V -> transposed scatter into vt.
__global__ __launch_bounds__(256) void gemm_qkv(const u16* __restrict__ A,
                                                const u16* __restrict__ Bt,
                                                u16* __restrict__ qkb,
                                                u16* __restrict__ vt,
                                                float qscale) {
  __shared__ __attribute__((aligned(16))) u16 As[2][2][128][32];  // 32 KB
  __shared__ __attribute__((aligned(16))) u16 Bs[2][2][128][32];  // 32 KB
  const int K = Dn;
  const int t = threadIdx.x;
  const int wave = t >> 6;
  const int lane = t & 63;
  const int lcol = lane & 15;
  const int quad = lane >> 4;
  const int wm = (wave >> 1) * 64;
  const int wn = (wave & 1) * 64;
  const int bm = blockIdx.y * 128;
  const int bn = blockIdx.x * 128;

  const int srow = lane >> 2;
  const int sseg = (lane & 3) * 8;
  const u16* a0p = A + (size_t)(bm + wave * 16 + srow) * K + sseg;
  const u16* a1p = a0p + (size_t)64 * K;
  const u16* b0p = Bt + (size_t)(bn + wave * 16 + srow) * K + sseg;
  const u16* b1p = b0p + (size_t)64 * K;
  u16* asl = &As[0][0][0][0] + wave * 512 + lane * 8;  // buf stride 8192 u16
  u16* bsl = &Bs[0][0][0][0] + wave * 512 + lane * 8;

  auto stage = [&](int k0, int d) {
    u16* as = asl + d * 8192;
    u16* bs = bsl + d * 8192;
    gl2lds16(a0p + k0, as);
    gl2lds16(a1p + k0, as + 2048);
    gl2lds16(a0p + k0 + 32, as + 4096);
    gl2lds16(a1p + k0 + 32, as + 6144);
    gl2lds16(b0p + k0, bs);
    gl2lds16(b1p + k0, bs + 2048);
    gl2lds16(b0p + k0 + 32, bs + 4096);
    gl2lds16(b1p + k0 + 32, bs + 6144);
  };

  f32x4 acc[4][4];
#pragma unroll
  for (int i = 0; i < 4; i++)
#pragma unroll
    for (int j = 0; j < 4; j++) acc[i][j] = (f32x4){0.f, 0.f, 0.f, 0.f};

  stage(0, 0);
  int d = 0;
  for (int k0 = 0; k0 < K; k0 += 64, d ^= 1) {
    __syncthreads();  // buf[d] DMA drained; buf[d^1] reads (prev iter) done
    if (k0 + 64 < K) stage(k0 + 64, d ^ 1);  // in flight during compute
#pragma unroll
    for (int ks = 0; ks < 2; ks++) {
      bf16x8 af[4], bf[4];
#pragma unroll
      for (int mi = 0; mi < 4; mi++)
        af[mi] = *(const bf16x8*)(&As[d][ks][wm + mi * 16 + lcol][quad * 8]);
#pragma unroll
      for (int ni = 0; ni < 4; ni++)
        bf[ni] = *(const bf16x8*)(&Bs[d][ks][wn + ni * 16 + lcol][quad * 8]);
#pragma unroll
      for (int mi = 0; mi < 4; mi++)
#pragma unroll
        for (int ni = 0; ni < 4; ni++)
          acc[mi][ni] = __builtin_amdgcn_mfma_f32_16x16x32_bf16(af[mi], bf[ni], acc[mi][ni], 0, 0, 0);
    }
  }

  if (bn >= 2048) {
    const int b = bm >> 11;
#pragma unroll
    for (int mi = 0; mi < 4; mi++) {
#pragma unroll
      for (int ni = 0; ni < 4; ni++) {
        int row0 = bm + wm + mi * 16 + quad * 4;
        int s = row0 & (Sn - 1);
        int vcol = bn + wn + ni * 16 + lcol - 2048;
        int bh = (b << 4) + (vcol >> 6);
        int hd = vcol & 63;
        unsigned d0 = (unsigned)f2bf(acc[mi][ni][0]) |
                      ((unsigned)f2bf(acc[mi][ni][1]) << 16);
        unsigned d1 = (unsigned)f2bf(acc[mi][ni][2]) |
                      ((unsigned)f2bf(acc[mi][ni][3]) << 16);
        *(uint2*)(vt + ((size_t)bh * HDn + hd) * Sn + s) = (uint2){d0, d1};
      }
    }
  } else {
    const float scale = (bn < 1024) ? qscale : 1.0f;
#pragma unroll
    for (int mi = 0; mi < 4; mi++) {
#pragma unroll
      for (int ni = 0; ni < 4; ni++) {
#pragma unroll
        for (int r = 0; r < 4; r++) {
          int row = bm + wm + mi * 16 + quad * 4 + r;
          int col = bn + wn + ni * 16 + lcol;
          qkb[(size_t)row * 2048 + col] = f2bf(acc[mi][ni][r] * scale);
        }
      }
    }
  }
}

// ---- output gemm: [8192 x 1024] fp32+bias, 128x128 tile, BK=64, DBUF ----
__global__ __launch_bounds__(256) void gemm_out(const u16* __restrict__ A,
                                                const u16* __restrict__ Bt,
                                                float* __restrict__ Cout,
                                                const float* __restrict__ bias) {
  __shared__ __attribute__((aligned(16))) u16 As[2][2][128][32];
  __shared__ __attribute__((aligned(16))) u16 Bs[2][2][128][32];
  const int K = Dn;
  const int t = threadIdx.x;
  const int wave = t >> 6;
  const int lane = t & 63;
  const int lcol = lane & 15;
  const int quad = lane >> 4;
  const int wm = (wave >> 1) * 64;
  const int wn = (wave & 1) * 64;
  const int bm = blockIdx.y * 128;
  const int bn = blockIdx.x * 128;

  const int srow = lane >> 2;
  const int sseg = (lane & 3) * 8;
  const u16* a0p = A + (size_t)(bm + wave * 16 + srow) * K + sseg;
  const u16* a1p = a0p + (size_t)64 * K;
  const u16* b0p = Bt + (size_t)(bn + wave * 16 + srow) * K + sseg;
  const u16* b1p = b0p + (size_t)64 * K;
  u16* asl = &As[0][0][0][0] + wave * 512 + lane * 8;
  u16* bsl = &Bs[0][0][0][0] + wave * 512 + lane * 8;

  auto stage = [&](int k0, int d) {
    u16* as = asl + d * 8192;
    u16* bs = bsl + d * 8192;
    gl2lds16(a0p + k0, as);
    gl2lds16(a1p + k0, as + 2048);
    gl2lds16(a0p + k0 + 32, as + 4096);
    gl2lds16(a1p + k0 + 32, as + 6144);
    gl2lds16(b0p + k0, bs);
    gl2lds16(b1p + k0, bs + 2048);
    gl2lds16(b0p + k0 + 32, bs + 4096);
    gl2lds16(b1p + k0 + 32, bs + 6144);
  };

  f32x4 acc[4][4];
#pragma unroll
  for (int i = 0; i < 4; i++)
#pragma unroll
    for (int j = 0; j < 4; j++) acc[i][j] = (f32x4){0.f, 0.f, 0.f, 0.f};

  stage(0, 0);
  int d = 0;
  for (int k0 = 0; k0 < K; k0 += 64, d ^= 1) {
    __syncthreads();
    if (k0 + 64 < K) stage(k0 + 64, d ^ 1);
#pragma unroll
    for (int ks = 0; ks < 2; ks++) {
      bf16x8 af[4], bf[4];
#pragma unroll
      for (int mi = 0; mi < 4; mi++)
        af[mi] = *(const bf16x8*)(&As[d][ks][wm + mi * 16 + lcol][quad * 8]);
#pragma unroll
      for (int ni = 0; ni < 4; ni++)
        bf[ni] = *(const bf16x8*)(&Bs[d][ks][wn + ni * 16 + lcol][quad * 8]);
#pragma unroll
      for (int mi = 0; mi < 4; mi++)
#pragma unroll
        for (int ni = 0; ni < 4; ni++)
          acc[mi][ni] = __builtin_amdgcn_mfma_f32_16x16x32_bf16(af[mi], bf[ni], acc[mi][ni], 0, 0, 0);
    }
  }

#pragma unroll
  for (int mi = 0; mi < 4; mi++) {
#pragma unroll
    for (int ni = 0; ni < 4; ni++) {
#pragma unroll
      for (int r = 0; r < 4; r++) {
        int row = bm + wm + mi * 16 + quad * 4 + r;
        int col = bn + wn + ni * 16 + lcol;
        Cout[(size_t)row * Dn + col] = acc[mi][ni][r] + bias[col];
      }
    }
  }
}

// ---- causal flash attention v5: paired strips for uniform load ----
__global__ __launch_bounds__(256, 2) void attn5(const u16* __restrict__ QK,
                                                const u16* __restrict__ Vt,
                                                u16* __restrict__ ctx) {
  __shared__ __attribute__((aligned(16))) u16 Ks2[2][64][32];
  __shared__ __attribute__((aligned(16))) u16 Vts2[2][64][32];
  __shared__ __attribute__((aligned(16))) u16 Pt[4][32][72];

  const int bh = blockIdx.x;
  const int b = bh >> 4, h = bh & 15;
  const int pair = blockIdx.y;           // 0..7
  const int t = threadIdx.x;
  const int w = t >> 6;
  const int lane = t & 63;
  const int lcol = lane & 15;
  const int quad = lane >> 4;
  const int qw0 = pair * 128 + w * 32;          // short strip wave base
  const int qw1 = (15 - pair) * 128 + w * 32;   // long strip wave base

  const size_t qkbase = ((size_t)b * Sn) * 2048 + h * HDn;
  const size_t obase = ((size_t)b * Sn) * Dn + h * HDn;
  const size_t vbase = ((size_t)bh * HDn) * Sn;

  bf16x8 qf[2][2][2];  // [strip][qb][kc]
#pragma unroll
  for (int si = 0; si < 2; si++) {
    const int qws = si ? qw1 : qw0;
#pragma unroll
    for (int qb = 0; qb < 2; qb++) {
      const u16* qp = QK + qkbase + (size_t)(qws + qb * 16 + lcol) * 2048 + quad * 8;
      qf[si][qb][0] = *(const bf16x8*)qp;
      qf[si][qb][1] = *(const bf16x8*)(qp + 32);
    }
  }

  f32x4 o[2][2][4];  // [strip][qb][nb]
#pragma unroll
  for (int si = 0; si < 2; si++)
#pragma unroll
    for (int qb = 0; qb < 2; qb++)
#pragma unroll
      for (int nb = 0; nb < 4; nb++) o[si][qb][nb] = (f32x4){0.f, 0.f, 0.f, 0.f};
  float lsum[2][2] = {{0.f, 0.f}, {0.f, 0.f}};

  const int srow = lane >> 2;
  const int sseg = (lane & 3) * 8;
  const u16* kp0 = QK + qkbase + 1024 + (size_t)(w * 16 + srow) * 2048 + sseg;
  const u16* vp0 = Vt + vbase + (size_t)(w * 16 + srow) * Sn + sseg;
  u16* ksl0 = &Ks2[0][0][0] + w * 512 + lane * 8;
  u16* ksl1 = ksl0 + 2048;
  u16* vsl0 = &Vts2[0][0][0] + w * 512 + lane * 8;
  u16* vsl1 = vsl0 + 2048;

  auto do_strip = [&](int si, int qw, int j0) {
    f32x4 s[4][2];
#pragma unroll
    for (int mb = 0; mb < 4; mb++) {
      bf16x8 kf0 = *(const bf16x8*)(&Ks2[0][mb * 16 + lcol][quad * 8]);
      bf16x8 kf1 = *(const bf16x8*)(&Ks2[1][mb * 16 + lcol][quad * 8]);
#pragma unroll
      for (int qb = 0; qb < 2; qb++) {
        f32x4 a = (f32x4){0.f, 0.f, 0.f, 0.f};
        a = __builtin_amdgcn_mfma_f32_16x16x32_bf16(kf0, qf[si][qb][0], a, 0, 0, 0);
        a = __builtin_amdgcn_mfma_f32_16x16x32_bf16(kf1, qf[si][qb][1], a, 0, 0, 0);
        s[mb][qb] = a;
      }
    }

    const bool needmask = (j0 + 63 > qw);
#pragma unroll
    for (int qb = 0; qb < 2; qb++) {
      const int qrow = qw + qb * 16 + lcol;
#pragma unroll
      for (int mb = 0; mb < 4; mb++) {
        float p[4];
#pragma unroll
        for (int r = 0; r < 4; r++) p[r] = fexp2(s[mb][qb][r]);
        if (needmask) {
          const int kvb = j0 + mb * 16 + quad * 4;
#pragma unroll
          for (int r = 0; r < 4; r++)
            if (kvb + r > qrow) p[r] = 0.f;
        }
        lsum[si][qb] += (p[0] + p[1]) + (p[2] + p[3]);
        unsigned d0 = pk_bf_trunc(p[0], p[1]);
        unsigned d1 = pk_bf_trunc(p[2], p[3]);
        *(uint2*)(&Pt[w][qb * 16 + lcol][mb * 16 + quad * 4]) = (uint2){d0, d1};
      }
    }

#pragma unroll
    for (int c = 0; c < 2; c++) {
      bf16x8 pf0 = *(const bf16x8*)(&Pt[w][lcol][c * 32 + quad * 8]);
      bf16x8 pf1 = *(const bf16x8*)(&Pt[w][16 + lcol][c * 32 + quad * 8]);
#pragma unroll
      for (int nb = 0; nb < 4; nb++) {
        bf16x8 vf = *(const bf16x8*)(&Vts2[c][nb * 16 + lcol][quad * 8]);
        o[si][0][nb] = __builtin_amdgcn_mfma_f32_16x16x32_bf16(vf, pf0, o[si][0][nb], 0, 0, 0);
        o[si][1][nb] = __builtin_amdgcn_mfma_f32_16x16x32_bf16(vf, pf1, o[si][1][nb], 0, 0, 0);
      }
    }
  };

  const int n_kv = (15 - pair) * 128 + 128;  // long strip upper bound

  for (int j0 = 0; j0 < n_kv; j0 += 64) {
    {
      const u16* kp = kp0 + (size_t)j0 * 2048;
      gl2lds16(kp, ksl0);
      gl2lds16(kp + 32, ksl1);
      const u16* vp = vp0 + j0;
      gl2lds16(vp, vsl0);
      gl2lds16(vp + 32, vsl1);
    }
    __syncthreads();

    if (j0 <= qw1 + 31) do_strip(1, qw1, j0);  // long strip
    if (j0 <= qw0 + 31) do_strip(0, qw0, j0);  // short strip
    __syncthreads();
  }

#pragma unroll
  for (int si = 0; si < 2; si++) {
    const int qws = si ? qw1 : qw0;
#pragma unroll
    for (int qb = 0; qb < 2; qb++) {
      float l = lsum[si][qb];
      l += __shfl_xor(l, 16);
      l += __shfl_xor(l, 32);
      float inv = 1.0f / l;
#pragma unroll
      for (int nb = 0; nb < 4; nb++) {
        unsigned d0 = (unsigned)f2bf(o[si][qb][nb][0] * inv) |
                      ((unsigned)f2bf(o[si][qb][nb][1] * inv) << 16);
        unsigned d1 = (unsigned)f2bf(o[si][qb][nb][2] * inv) |
                      ((unsigned)f2bf(o[si][qb][nb][3] * inv) << 16);
        u16* p = ctx + obase + (size_t)(qws + qb * 16 + lcol) * Dn + nb * 16 + quad * 4;
        *(uint2*)p = (uint2){d0, d1};
      }
    }
  }
}

extern "C" void kernel_launch(void* const* d_in, const int* in_sizes, int n_in,
                              void* d_out, int out_size, void* d_ws, size_t ws_size,
                              hipStream_t stream) {
  const float* x  = (const float*)d_in[0];
  const float* Wq = (const float*)d_in[1];
  const float* Wk = (const float*)d_in[2];
  const float* Wv = (const float*)d_in[3];
  const float* Wo = (const float*)d_in[4];
  const float* bo = (const float*)d_in[5];
  float* out = (float*)d_out;

  const size_t BSD = (size_t)Bn * Sn * Dn;
  const size_t DD = (size_t)Dn * Dn;

  u16* xb    = (u16*)d_ws;           // BSD
  u16* wall  = xb + BSD;             // 4*DD  (Wq^T, Wk^T, Wv^T, Wo^T)
  u16* qkb   = wall + 4 * DD;        // 2*BSD
  u16* vt    = qkb + 2 * BSD;        // BSD
  u16* cb    = vt + BSD;             // BSD

  cvt4<<<(int)(BSD / 4 / 256), 256, 0, stream>>>(x, xb, (int)(BSD / 4));
  tcvt4<<<dim3(Dn / 32, Dn / 32, 4), 256, 0, stream>>>(Wq, Wk, Wv, Wo, wall);

  // fused QKV projection: 128x128 tiles, 1536 blocks, dbuf DMA
  gemm_qkv<<<dim3(3072 / 128, (Bn * Sn) / 128), 256, 0, stream>>>(
      xb, wall, qkb, vt, 0.125f * 1.44269504f);

  attn5<<<dim3(Bn * Hn, 8), 256, 0, stream>>>(qkb, vt, cb);

  // output projection: 128x128 tiles, 512 blocks, dbuf DMA
  gemm_out<<<dim3(Dn / 128, (Bn * Sn) / 128), 256, 0, stream>>>(cb, wall + 3 * DD, out, bo);
}